// Round 11
// baseline (172.587 us; speedup 1.0000x reference)
//
#include <hip/hip_runtime.h>
#include <math.h>
#include <stdint.h>

// ---------------- model constants ----------------
#define BATCH 65536
#define TB 128           // 4 waves x 32 rows (one 32x32 m-tile each), independent

typedef __fp16   fp16x2  __attribute__((ext_vector_type(2)));   // cvt_pkrtz result
typedef _Float16 half8   __attribute__((ext_vector_type(8)));
typedef float    floatx16 __attribute__((ext_vector_type(16)));

// per-wave LDS strides (halves)
#define SH 68            // hH: 64 cols + 4 pad  (34 dwords ≡ 2 mod 32: 2-way = free)
#define SM 130           // hM: 129 cols + 1     (65 dwords, odd: conflict-free)
#define HM_SLICE (32*SM + 64)   // +64 zeroed tail halves (silu b128 overrun, row 31)

// packed-weight geometry (f16), FRAGMENT-ORDERED for 32x32x16:
//   element (ks, nt, lane, j) at ((ks*NT + nt)*512) + lane*8 + j
//   maps to B[k = ks*16 + (lane>>5)*8 + j][n = nt*32 + (lane&31)]
// -> wave's B-frag load = base + lane*16B: one coalesced 1KB transaction.
#define WIN 2048          // stage1: 2 ksteps x 2 ntiles x 512
#define KSA 36            // a: 32 spline ksteps (512 k) + 4 silu (64)  (36 % 4 == 0)
#define KSB 76            // b: 65 spline (1032 real k) + 11 silu (129 real) (76 % 4 == 0)
#define WA (KSA*5*512)    // 92160  (O=129 -> 5 n-tiles of 32)
#define WB (KSB*2*512)    // 77824  (O=64  -> 2 n-tiles)
#define WTOT (WIN + 2*(WA+WB))   // 342016 halfs = 684032 B of d_ws

// ---------------------------------------------------------------------------
// setup: pack all weights f16 in 32x32-fragment order.
// spline slot k=8i+p -> ss*coef; silu -> sb; zero outside real I/O.
// ---------------------------------------------------------------------------
__global__ void setup_weights(
    const float* __restrict__ W_in,
    const float* __restrict__ c0a, const float* __restrict__ sb0a, const float* __restrict__ ss0a,
    const float* __restrict__ c0b, const float* __restrict__ sb0b, const float* __restrict__ ss0b,
    const float* __restrict__ c1a, const float* __restrict__ sb1a, const float* __restrict__ ss1a,
    const float* __restrict__ c1b, const float* __restrict__ sb1b, const float* __restrict__ ss1b,
    _Float16* __restrict__ wt) {
  int idx = blockIdx.x * 256 + threadIdx.x;
  if (idx >= WTOT) return;
  float v = 0.0f;
  if (idx < WIN) {                        // W_in [32][64]: (ks*2+nt)*512 order
    int ks = idx >> 10; int nt = (idx >> 9) & 1;
    int q = idx & 511;  int l = q >> 3;   int j = q & 7;
    int n = nt*32 + (l & 31);
    int k = ks*16 + (l >> 5)*8 + j;
    v = W_in[k*64 + n];
  } else {
    int e2   = idx - WIN;
    int pair = (e2 >= WA + WB) ? 1 : 0;
    int e    = e2 - pair * (WA + WB);
    if (e < WA) {                         // a-type: I=64, O=129 (5 n-tiles)
      const float* coef = pair ? c1a : c0a;
      const float* sb   = pair ? sb1a : sb0a;
      const float* ss   = pair ? ss1a : ss0a;
      int ks = e / 2560; int r = e - ks*2560;
      int nt = r >> 9;   int q = r & 511;
      int l  = q >> 3;   int j = q & 7;
      int n  = nt*32 + (l & 31);
      int k  = ks*16 + (l >> 5)*8 + j;    // k < 576
      if (n < 129) {
        if (k < 512) { int i = k >> 3, p = k & 7; v = ss[i*129+n] * coef[(i*129+n)*8 + p]; }
        else         { int i = k - 512; if (i < 64) v = sb[i*129+n]; }
      }
    } else {                              // b-type: I=129, O=64 (2 n-tiles)
      const float* coef = pair ? c1b : c0b;
      const float* sb   = pair ? sb1b : sb0b;
      const float* ss   = pair ? ss1b : ss0b;
      int eb = e - WA;
      int ks = eb >> 10; int r = eb & 1023;
      int nt = r >> 9;   int q = r & 511;
      int l  = q >> 3;   int j = q & 7;
      int n  = nt*32 + (l & 31);
      int k  = ks*16 + (l >> 5)*8 + j;    // k < 1232
      if (k < 1032)      { int i = k >> 3, p = k & 7; v = ss[i*64+n] * coef[(i*64+n)*8 + p]; }
      else if (k >= 1040){ int s = k - 1040; if (s < 129) v = sb[s*64+n]; }
      // k in [1032,1040) and s >= 129: dead pad slots -> 0
    }
  }
  wt[idx] = (_Float16)v;
}

// ---------------------------------------------------------------------------
// feat8: 8 B-spline basis values of x as a ready A-fragment (8 halfs).
// Funnel-shift placement + cvt_pkrtz packing (validated r8-r10, absmax 0.0078).
// ---------------------------------------------------------------------------
__device__ __forceinline__ half8 feat8(float x) {
  float s  = fmaf(x, 2.5f, 5.5f);          // (x+2.2)*2.5
  float mf = floorf(s);
  int   m  = (int)mf;
  float u  = s - mf;
  float t  = 1.0f - u;
  float u2 = u*u;
  float w0 = t*t*t * (1.0f/6.0f);
  float w3 = u2*u * (1.0f/6.0f);
  float w1 = fmaf(u2, fmaf(0.5f, u, -1.0f), 2.0f/3.0f);   // (3u^3-6u^2+4)/6
  float w2 = 1.0f - w0 - w1 - w3;                          // partition of unity
  union { fp16x2 h2[2]; uint64_t u64; } P;
  P.h2[0] = __builtin_amdgcn_cvt_pkrtz(w0, w1);
  P.h2[1] = __builtin_amdgcn_cvt_pkrtz(w2, w3);
  uint64_t w01 = ((unsigned)m <= 10u) ? P.u64 : 0ull;
  int sh = (m - 3) * 16;                                   // bits; [-48,112] valid
  uint64_t q0 = (sh >= 0) ? ((sh < 64) ? (w01 << sh) : 0ull) : (w01 >> (-sh));
  uint64_t q1 = (sh >= 64) ? (w01 << (sh - 64))
                           : ((sh > 0) ? (w01 >> (64 - sh)) : 0ull);
  union { uint64_t q[2]; half8 h; } R;
  R.q[0] = q0; R.q[1] = q1;
  return R.h;
}

// ---------------------------------------------------------------------------
// one KAN layer, per-wave 32 rows = one 32x32 m-tile. A-frags in registers.
// Depth-4 B-pipeline via modular slot (ks & 3), use-then-refill, unroll 4:
// all slot indices compile-time -> zero rotation movs, loads 4 k-steps ahead.
// ---------------------------------------------------------------------------
template<int KSPL, int KSIL, int NT, int SIN, int O, int SOUT>
__device__ __forceinline__ void kan_layer(
    const _Float16* __restrict__ hinw, _Float16* __restrict__ houtw,
    const _Float16* __restrict__ wt, const float* __restrict__ bias, int lane) {
  constexpr int KTOT = KSPL + KSIL;            // multiple of 4
  static_assert(KTOT % 4 == 0, "KTOT must be a multiple of 4");
  const int ln = lane & 31;
  const int kh = lane >> 5;
  const half8* __restrict__ bp = (const half8*)wt + lane;   // +lane*16B
  floatx16 acc[NT];
  #pragma unroll
  for (int j = 0; j < NT; ++j)
    #pragma unroll
    for (int e = 0; e < 16; ++e) acc[j][e] = 0.0f;

  half8 B[4][NT];                              // depth-4 prefetch pipeline
  #pragma unroll
  for (int d = 0; d < 4; ++d)
    #pragma unroll
    for (int j = 0; j < NT; ++j) B[d][j] = bp[(d*NT + j)*64];

  #pragma unroll 4
  for (int ks = 0; ks < KTOT; ++ks) {
    const int slot = ks & 3;                   // compile-time under unroll 4
    // ---- A-fragment in registers ----
    half8 A;
    if (ks < KSPL) {                           // spline: input i = 2ks + kh
      float xv = (float)hinw[ln*SIN + 2*ks + kh];
      A = feat8(xv);
    } else {                                   // silu: slots sk*16 + kh*8 ..
      int sk = ks - KSPL;
      half8 h8 = *(const half8*)&hinw[ln*SIN + sk*16 + kh*8];
      union { fp16x2 h2[4]; half8 v; } Au;
      #pragma unroll
      for (int e = 0; e < 4; ++e) {
        float x0 = (float)h8[2*e], x1 = (float)h8[2*e + 1];
        float s0 = x0 / (1.0f + __expf(-x0));
        float s1 = x1 / (1.0f + __expf(-x1));
        Au.h2[e] = __builtin_amdgcn_cvt_pkrtz(s0, s1);
      }
      A = Au.v;
    }
    // ---- use slot, then refill with ks+4 (clamped; tail re-loads last) ----
    half8 Bc[NT];
    #pragma unroll
    for (int j = 0; j < NT; ++j) Bc[j] = B[slot][j];
    const int nks = (ks + 4 < KTOT) ? (ks + 4) : (KTOT - 1);
    #pragma unroll
    for (int j = 0; j < NT; ++j) B[slot][j] = bp[(nks*NT + j)*64];
    // ---- MFMAs ----
    #pragma unroll
    for (int j = 0; j < NT; ++j)
      acc[j] = __builtin_amdgcn_mfma_f32_32x32x16_f16(A, Bc[j], acc[j], 0, 0, 0);
  }

  // ---- epilogue: C/D col=lane&31, row=(reg&3)+8*(reg>>2)+4*(lane>>5) ----
  #pragma unroll
  for (int j = 0; j < NT; ++j) {
    int col = j*32 + ln;
    if (col < O) {
      float bv = bias[col];
      #pragma unroll
      for (int r = 0; r < 16; ++r) {
        int row = (r & 3) + 8*(r >> 2) + 4*kh;
        houtw[row*SOUT + col] = (_Float16)(acc[j][r] + bv);
      }
    }
  }
}

// ---------------------------------------------------------------------------
// fused forward, zero __syncthreads, 32x32 MFMA, depth-4 B prefetch.
// LDS = 4*(32*130+64 + 32*68)*2 = 51200 B -> 2 blocks/CU; grid 512 = exact.
// ---------------------------------------------------------------------------
extern "C" __global__ void __launch_bounds__(256, 2)
kan_forward(const float* __restrict__ x, const float* __restrict__ b_in,
            const float* __restrict__ W_out, const _Float16* __restrict__ wt,
            const float* __restrict__ bias0a, const float* __restrict__ bias0b,
            const float* __restrict__ bias1a, const float* __restrict__ bias1b,
            float* __restrict__ out) {
  __shared__ _Float16 hM[4][HM_SLICE];
  __shared__ _Float16 hH[4][32*SH];
  const int t    = threadIdx.x;
  const int wv   = t >> 6;
  const int lane = t & 63;
  const int ln   = lane & 31;
  const int kh   = lane >> 5;
  _Float16* hMw = hM[wv];
  _Float16* hHw = hH[wv];
  const int rbase = blockIdx.x * TB + wv * 32;

  // zero hM spots padded reads can touch: col 129 each row + tail pad
  hMw[32*SM + lane] = (_Float16)0.0f;
  if (lane < 32) hMw[lane*SM + 129] = (_Float16)0.0f;

  // stage 1: hH = relu(x @ W_in + b_in). Two k-steps, 2 n-tiles.
  {
    const float* xr = &x[(rbase + ln)*32 + kh*8];
    float4 v0 = *(const float4*)&xr[0];
    float4 v1 = *(const float4*)&xr[4];
    float4 v2 = *(const float4*)&xr[16];
    float4 v3 = *(const float4*)&xr[20];
    union { fp16x2 h2[4]; half8 h8; } A0, A1;
    A0.h2[0] = __builtin_amdgcn_cvt_pkrtz(v0.x, v0.y);
    A0.h2[1] = __builtin_amdgcn_cvt_pkrtz(v0.z, v0.w);
    A0.h2[2] = __builtin_amdgcn_cvt_pkrtz(v1.x, v1.y);
    A0.h2[3] = __builtin_amdgcn_cvt_pkrtz(v1.z, v1.w);
    A1.h2[0] = __builtin_amdgcn_cvt_pkrtz(v2.x, v2.y);
    A1.h2[1] = __builtin_amdgcn_cvt_pkrtz(v2.z, v2.w);
    A1.h2[2] = __builtin_amdgcn_cvt_pkrtz(v3.x, v3.y);
    A1.h2[3] = __builtin_amdgcn_cvt_pkrtz(v3.z, v3.w);
    const half8* bp = (const half8*)wt + lane;
    #pragma unroll
    for (int nt = 0; nt < 2; ++nt) {
      floatx16 a;
      #pragma unroll
      for (int e = 0; e < 16; ++e) a[e] = 0.0f;
      a = __builtin_amdgcn_mfma_f32_32x32x16_f16(A0.h8, bp[nt*64],       a, 0, 0, 0);
      a = __builtin_amdgcn_mfma_f32_32x32x16_f16(A1.h8, bp[(2 + nt)*64], a, 0, 0, 0);
      int col = nt*32 + ln;
      float bv = b_in[col];
      #pragma unroll
      for (int r = 0; r < 16; ++r) {
        int row = (r & 3) + 8*(r >> 2) + 4*kh;
        hHw[row*SH + col] = (_Float16)fmaxf(a[r] + bv, 0.0f);
      }
    }
  }

  kan_layer<32, 4,5,SH,129,SM>(hHw, hMw, wt + WIN,             bias0a, lane);
  kan_layer<65,11,2,SM, 64,SH>(hMw, hHw, wt + WIN + WA,        bias0b, lane);
  kan_layer<32, 4,5,SH,129,SM>(hHw, hMw, wt + WIN + WA + WB,   bias1a, lane);
  kan_layer<65,11,2,SM, 64,SH>(hMw, hHw, wt + WIN + 2*WA + WB, bias1b, lane);

  // final: out = sigmoid(hH @ W_out); two col-halves reduced by shuffle
  {
    float s = 0.0f;
    #pragma unroll
    for (int j = 0; j < 32; ++j)
      s = fmaf((float)hHw[ln*SH + kh*32 + j], W_out[kh*32 + j], s);
    s += __shfl_down(s, 32);
    if (lane < 32) out[rbase + ln] = 1.0f / (1.0f + __expf(-s));
  }
}

// ---------------------------------------------------------------------------
extern "C" void kernel_launch(void* const* d_in, const int* in_sizes, int n_in,
                              void* d_out, int out_size, void* d_ws, size_t ws_size,
                              hipStream_t stream) {
  const float* x     = (const float*)d_in[0];
  const float* W_in  = (const float*)d_in[1];
  const float* b_in  = (const float*)d_in[2];
  const float* W_out = (const float*)d_in[3];
  const float* c0a = (const float*)d_in[4];  const float* sb0a = (const float*)d_in[5];
  const float* ss0a= (const float*)d_in[6];  const float* bias0a=(const float*)d_in[7];
  const float* c0b = (const float*)d_in[8];  const float* sb0b = (const float*)d_in[9];
  const float* ss0b= (const float*)d_in[10]; const float* bias0b=(const float*)d_in[11];
  const float* c1a = (const float*)d_in[12]; const float* sb1a = (const float*)d_in[13];
  const float* ss1a= (const float*)d_in[14]; const float* bias1a=(const float*)d_in[15];
  const float* c1b = (const float*)d_in[16]; const float* sb1b = (const float*)d_in[17];
  const float* ss1b= (const float*)d_in[18]; const float* bias1b=(const float*)d_in[19];
  float*    out = (float*)d_out;
  _Float16* wt  = (_Float16*)d_ws;       // 684,032 B scratch, repacked every call

  setup_weights<<<(WTOT + 255)/256, 256, 0, stream>>>(
      W_in, c0a, sb0a, ss0a, c0b, sb0b, ss0b,
      c1a, sb1a, ss1a, c1b, sb1b, ss1b, wt);

  kan_forward<<<BATCH/TB, 256, 0, stream>>>(
      x, b_in, W_out, wt, bias0a, bias0b, bias1a, bias1b, out);
}

// Round 12
// 165.745 us; speedup vs baseline: 1.0413x; 1.0413x over previous
//
#include <hip/hip_runtime.h>
#include <math.h>
#include <stdint.h>

// ---------------- model constants ----------------
#define BATCH 65536
#define TB 128           // 4 waves x 32 rows (one 32x32 m-tile each), independent

typedef __fp16   fp16x2  __attribute__((ext_vector_type(2)));   // cvt_pkrtz result
typedef _Float16 half8   __attribute__((ext_vector_type(8)));
typedef float    floatx16 __attribute__((ext_vector_type(16)));

// per-wave LDS strides (halves)
#define SH 68            // hH: 64 cols + 4 pad
#define SM 130           // hM: 129 cols + 1
#define HM_SLICE (32*SM + 64)   // +64 zeroed tail halves (b128 overrun, row 31)

// packed-weight geometry (f16), FRAGMENT-ORDERED for 32x32x16 (same as r11):
//   element (ks, nt, lane, j) at ((ks*NT + nt)*512) + lane*8 + j
//   maps to B[k = ks*16 + (lane>>5)*8 + j][n = nt*32 + (lane&31)]
#define WIN 2048          // stage1: 2 ksteps x 2 ntiles x 512
#define KSA 36            // a: 32 spline ksteps + 4 silu
#define KSB 76            // b: 65 spline ksteps (1032 real k) + 11 silu (129 real)
#define WA (KSA*5*512)    // 92160
#define WB (KSB*2*512)    // 77824
#define WTOT (WIN + 2*(WA+WB))   // 342016 halfs = 684032 B of d_ws

// ---------------------------------------------------------------------------
// setup: pack all weights f16 in 32x32-fragment order (identical to r11).
// ---------------------------------------------------------------------------
__global__ void setup_weights(
    const float* __restrict__ W_in,
    const float* __restrict__ c0a, const float* __restrict__ sb0a, const float* __restrict__ ss0a,
    const float* __restrict__ c0b, const float* __restrict__ sb0b, const float* __restrict__ ss0b,
    const float* __restrict__ c1a, const float* __restrict__ sb1a, const float* __restrict__ ss1a,
    const float* __restrict__ c1b, const float* __restrict__ sb1b, const float* __restrict__ ss1b,
    _Float16* __restrict__ wt) {
  int idx = blockIdx.x * 256 + threadIdx.x;
  if (idx >= WTOT) return;
  float v = 0.0f;
  if (idx < WIN) {                        // W_in [32][64]: (ks*2+nt)*512 order
    int ks = idx >> 10; int nt = (idx >> 9) & 1;
    int q = idx & 511;  int l = q >> 3;   int j = q & 7;
    int n = nt*32 + (l & 31);
    int k = ks*16 + (l >> 5)*8 + j;
    v = W_in[k*64 + n];
  } else {
    int e2   = idx - WIN;
    int pair = (e2 >= WA + WB) ? 1 : 0;
    int e    = e2 - pair * (WA + WB);
    if (e < WA) {                         // a-type: I=64, O=129 (5 n-tiles)
      const float* coef = pair ? c1a : c0a;
      const float* sb   = pair ? sb1a : sb0a;
      const float* ss   = pair ? ss1a : ss0a;
      int ks = e / 2560; int r = e - ks*2560;
      int nt = r >> 9;   int q = r & 511;
      int l  = q >> 3;   int j = q & 7;
      int n  = nt*32 + (l & 31);
      int k  = ks*16 + (l >> 5)*8 + j;    // k < 576
      if (n < 129) {
        if (k < 512) { int i = k >> 3, p = k & 7; v = ss[i*129+n] * coef[(i*129+n)*8 + p]; }
        else         { int i = k - 512; if (i < 64) v = sb[i*129+n]; }
      }
    } else {                              // b-type: I=129, O=64 (2 n-tiles)
      const float* coef = pair ? c1b : c0b;
      const float* sb   = pair ? sb1b : sb0b;
      const float* ss   = pair ? ss1b : ss0b;
      int eb = e - WA;
      int ks = eb >> 10; int r = eb & 1023;
      int nt = r >> 9;   int q = r & 511;
      int l  = q >> 3;   int j = q & 7;
      int n  = nt*32 + (l & 31);
      int k  = ks*16 + (l >> 5)*8 + j;    // k < 1216
      if (k < 1032)      { int i = k >> 3, p = k & 7; v = ss[i*64+n] * coef[(i*64+n)*8 + p]; }
      else if (k >= 1040){ int s = k - 1040; if (s < 129) v = sb[s*64+n]; }
      // k in [1032,1040) and s >= 129: dead pad slots -> 0
    }
  }
  wt[idx] = (_Float16)v;
}

// ---------------------------------------------------------------------------
// feat8: 8 B-spline basis values of x as a ready A-fragment (8 halfs).
// Funnel-shift placement + cvt_pkrtz packing (validated r8-r11, absmax 0.0078).
// ---------------------------------------------------------------------------
__device__ __forceinline__ half8 feat8(float x) {
  float s  = fmaf(x, 2.5f, 5.5f);          // (x+2.2)*2.5
  float mf = floorf(s);
  int   m  = (int)mf;
  float u  = s - mf;
  float t  = 1.0f - u;
  float u2 = u*u;
  float w0 = t*t*t * (1.0f/6.0f);
  float w3 = u2*u * (1.0f/6.0f);
  float w1 = fmaf(u2, fmaf(0.5f, u, -1.0f), 2.0f/3.0f);   // (3u^3-6u^2+4)/6
  float w2 = 1.0f - w0 - w1 - w3;                          // partition of unity
  union { fp16x2 h2[2]; uint64_t u64; } P;
  P.h2[0] = __builtin_amdgcn_cvt_pkrtz(w0, w1);
  P.h2[1] = __builtin_amdgcn_cvt_pkrtz(w2, w3);
  uint64_t w01 = ((unsigned)m <= 10u) ? P.u64 : 0ull;
  int sh = (m - 3) * 16;                                   // bits; [-48,112] valid
  uint64_t q0 = (sh >= 0) ? ((sh < 64) ? (w01 << sh) : 0ull) : (w01 >> (-sh));
  uint64_t q1 = (sh >= 64) ? (w01 << (sh - 64))
                           : ((sh > 0) ? (w01 >> (64 - sh)) : 0ull);
  union { uint64_t q[2]; half8 h; } R;
  R.q[0] = q0; R.q[1] = q1;
  return R.h;
}

// extract half #kh of dword w (khs = kh*16), as f32
__device__ __forceinline__ float extract_half(uint32_t w, int khs) {
  union { uint32_t u; _Float16 h[2]; } cv;
  cv.u = w >> khs;
  return (float)cv.h[0];
}

// ---------------------------------------------------------------------------
// one KAN layer, per-wave 32 rows = one 32x32 m-tile. A-frags in registers.
// r12: spline loop in groups of 8 k-steps — bulk-read 16 h-halfs as 2x half8
// per group (replaces ~90 scalar ds_reads/wave); zero-copy depth-2 B pipeline:
// step ks consumes B[ks&1] then refills the SAME slot with ks+2 (WAR reuse,
// no rotation movs; all slot indices compile-time).
// ---------------------------------------------------------------------------
template<int KSPL, int KSIL, int NT, int SIN, int O, int SOUT>
__device__ __forceinline__ void kan_layer(
    const _Float16* __restrict__ hinw, _Float16* __restrict__ houtw,
    const _Float16* __restrict__ wt, const float* __restrict__ bias, int lane) {
  constexpr int KTOT = KSPL + KSIL;
  constexpr int NG   = KSPL / 8;            // full spline groups
  constexpr int KR   = KSPL - NG*8;         // remainder spline steps (0 or 1)
  static_assert(KR == 0 || KR == 1, "remainder must be 0/1");
  const int ln  = lane & 31;
  const int kh  = lane >> 5;
  const int khs = kh << 4;
  const half8* __restrict__ bp = (const half8*)wt + lane;   // +lane*16B
  floatx16 acc[NT];
  #pragma unroll
  for (int j = 0; j < NT; ++j)
    #pragma unroll
    for (int e = 0; e < 16; ++e) acc[j][e] = 0.0f;

  half8 B[2][NT];                           // depth-2, zero-copy slots
  #pragma unroll
  for (int d = 0; d < 2; ++d)
    #pragma unroll
    for (int j = 0; j < NT; ++j) B[d][j] = bp[(d*NT + j)*64];

  union H8 { half8 h; uint32_t d[4]; };

  // ---- spline groups: 8 k-steps each; inputs 16g..16g+15 of row ln ----
  #pragma unroll 1
  for (int g = 0; g < NG; ++g) {
    H8 ha, hb;
    ha.h = *(const half8*)&hinw[ln*SIN + g*16];
    hb.h = *(const half8*)&hinw[ln*SIN + g*16 + 8];
    #pragma unroll
    for (int u = 0; u < 8; ++u) {
      uint32_t w = (u < 4) ? ha.d[u] : hb.d[u & 3];
      half8 A = feat8(extract_half(w, khs));     // input i = 2(g*8+u)+kh
      #pragma unroll
      for (int j = 0; j < NT; ++j)
        acc[j] = __builtin_amdgcn_mfma_f32_32x32x16_f16(A, B[u & 1][j], acc[j], 0, 0, 0);
      #pragma unroll
      for (int j = 0; j < NT; ++j)               // refill same slot with ks+2
        B[u & 1][j] = bp[((g*8 + u + 2)*NT + j)*64];
    }
  }

  // ---- remainder spline step (layer-b: ks = NG*8) ----
  if (KR == 1) {
    constexpr int ks = NG*8;
    H8 hc;
    hc.h = *(const half8*)&hinw[ln*SIN + ks*2];  // elems 2ks..2ks+7 (pads zeroed)
    half8 A = feat8(extract_half(hc.d[0], khs));
    #pragma unroll
    for (int j = 0; j < NT; ++j)
      acc[j] = __builtin_amdgcn_mfma_f32_32x32x16_f16(A, B[ks & 1][j], acc[j], 0, 0, 0);
    #pragma unroll
    for (int j = 0; j < NT; ++j)
      B[ks & 1][j] = bp[((ks + 2)*NT + j)*64];   // ks+2 < KTOT always (KSIL>=4)
  }

  // ---- silu k-steps (fully unrolled; slots compile-time) ----
  #pragma unroll
  for (int sk = 0; sk < KSIL; ++sk) {
    const int ks = KSPL + sk;
    half8 h8 = *(const half8*)&hinw[ln*SIN + sk*16 + kh*8];
    union { fp16x2 h2[4]; half8 v; } Au;
    #pragma unroll
    for (int e = 0; e < 4; ++e) {
      float x0 = (float)h8[2*e], x1 = (float)h8[2*e + 1];
      float s0 = x0 / (1.0f + __expf(-x0));
      float s1 = x1 / (1.0f + __expf(-x1));
      Au.h2[e] = __builtin_amdgcn_cvt_pkrtz(s0, s1);
    }
    #pragma unroll
    for (int j = 0; j < NT; ++j)
      acc[j] = __builtin_amdgcn_mfma_f32_32x32x16_f16(Au.v, B[ks & 1][j], acc[j], 0, 0, 0);
    const int nks = (ks + 2 < KTOT) ? (ks + 2) : (KTOT - 1);
    #pragma unroll
    for (int j = 0; j < NT; ++j)
      B[ks & 1][j] = bp[(nks*NT + j)*64];
  }

  // ---- epilogue: C/D col=lane&31, row=(reg&3)+8*(reg>>2)+4*(lane>>5) ----
  #pragma unroll
  for (int j = 0; j < NT; ++j) {
    int col = j*32 + ln;
    if (col < O) {
      float bv = bias[col];
      #pragma unroll
      for (int r = 0; r < 16; ++r) {
        int row = (r & 3) + 8*(r >> 2) + 4*kh;
        houtw[row*SOUT + col] = (_Float16)(acc[j][r] + bv);
      }
    }
  }
}

// ---------------------------------------------------------------------------
// fused forward, zero __syncthreads, 32x32 MFMA, zero-copy depth-2 pipeline.
// LDS = 51200 B -> 2 blocks/CU; grid 512 = exact.
// ---------------------------------------------------------------------------
extern "C" __global__ void __launch_bounds__(256, 2)
kan_forward(const float* __restrict__ x, const float* __restrict__ b_in,
            const float* __restrict__ W_out, const _Float16* __restrict__ wt,
            const float* __restrict__ bias0a, const float* __restrict__ bias0b,
            const float* __restrict__ bias1a, const float* __restrict__ bias1b,
            float* __restrict__ out) {
  __shared__ _Float16 hM[4][HM_SLICE];
  __shared__ _Float16 hH[4][32*SH];
  const int t    = threadIdx.x;
  const int wv   = t >> 6;
  const int lane = t & 63;
  const int ln   = lane & 31;
  const int kh   = lane >> 5;
  _Float16* hMw = hM[wv];
  _Float16* hHw = hH[wv];
  const int rbase = blockIdx.x * TB + wv * 32;

  // zero hM spots padded reads can touch: col 129 each row + tail pad
  hMw[32*SM + lane] = (_Float16)0.0f;
  if (lane < 32) hMw[lane*SM + 129] = (_Float16)0.0f;

  // stage 1: hH = relu(x @ W_in + b_in). Two k-steps, 2 n-tiles.
  {
    const float* xr = &x[(rbase + ln)*32 + kh*8];
    float4 v0 = *(const float4*)&xr[0];
    float4 v1 = *(const float4*)&xr[4];
    float4 v2 = *(const float4*)&xr[16];
    float4 v3 = *(const float4*)&xr[20];
    union { fp16x2 h2[4]; half8 h8; } A0, A1;
    A0.h2[0] = __builtin_amdgcn_cvt_pkrtz(v0.x, v0.y);
    A0.h2[1] = __builtin_amdgcn_cvt_pkrtz(v0.z, v0.w);
    A0.h2[2] = __builtin_amdgcn_cvt_pkrtz(v1.x, v1.y);
    A0.h2[3] = __builtin_amdgcn_cvt_pkrtz(v1.z, v1.w);
    A1.h2[0] = __builtin_amdgcn_cvt_pkrtz(v2.x, v2.y);
    A1.h2[1] = __builtin_amdgcn_cvt_pkrtz(v2.z, v2.w);
    A1.h2[2] = __builtin_amdgcn_cvt_pkrtz(v3.x, v3.y);
    A1.h2[3] = __builtin_amdgcn_cvt_pkrtz(v3.z, v3.w);
    const half8* bp = (const half8*)wt + lane;
    #pragma unroll
    for (int nt = 0; nt < 2; ++nt) {
      floatx16 a;
      #pragma unroll
      for (int e = 0; e < 16; ++e) a[e] = 0.0f;
      a = __builtin_amdgcn_mfma_f32_32x32x16_f16(A0.h8, bp[nt*64],       a, 0, 0, 0);
      a = __builtin_amdgcn_mfma_f32_32x32x16_f16(A1.h8, bp[(2 + nt)*64], a, 0, 0, 0);
      int col = nt*32 + ln;
      float bv = b_in[col];
      #pragma unroll
      for (int r = 0; r < 16; ++r) {
        int row = (r & 3) + 8*(r >> 2) + 4*kh;
        hHw[row*SH + col] = (_Float16)fmaxf(a[r] + bv, 0.0f);
      }
    }
  }

  kan_layer<32, 4,5,SH,129,SM>(hHw, hMw, wt + WIN,             bias0a, lane);
  kan_layer<65,11,2,SM, 64,SH>(hMw, hHw, wt + WIN + WA,        bias0b, lane);
  kan_layer<32, 4,5,SH,129,SM>(hHw, hMw, wt + WIN + WA + WB,   bias1a, lane);
  kan_layer<65,11,2,SM, 64,SH>(hMw, hHw, wt + WIN + 2*WA + WB, bias1b, lane);

  // final: out = sigmoid(hH @ W_out); two col-halves reduced by shuffle
  {
    float s = 0.0f;
    #pragma unroll
    for (int j = 0; j < 32; ++j)
      s = fmaf((float)hHw[ln*SH + kh*32 + j], W_out[kh*32 + j], s);
    s += __shfl_down(s, 32);
    if (lane < 32) out[rbase + ln] = 1.0f / (1.0f + __expf(-s));
  }
}

// ---------------------------------------------------------------------------
extern "C" void kernel_launch(void* const* d_in, const int* in_sizes, int n_in,
                              void* d_out, int out_size, void* d_ws, size_t ws_size,
                              hipStream_t stream) {
  const float* x     = (const float*)d_in[0];
  const float* W_in  = (const float*)d_in[1];
  const float* b_in  = (const float*)d_in[2];
  const float* W_out = (const float*)d_in[3];
  const float* c0a = (const float*)d_in[4];  const float* sb0a = (const float*)d_in[5];
  const float* ss0a= (const float*)d_in[6];  const float* bias0a=(const float*)d_in[7];
  const float* c0b = (const float*)d_in[8];  const float* sb0b = (const float*)d_in[9];
  const float* ss0b= (const float*)d_in[10]; const float* bias0b=(const float*)d_in[11];
  const float* c1a = (const float*)d_in[12]; const float* sb1a = (const float*)d_in[13];
  const float* ss1a= (const float*)d_in[14]; const float* bias1a=(const float*)d_in[15];
  const float* c1b = (const float*)d_in[16]; const float* sb1b = (const float*)d_in[17];
  const float* ss1b= (const float*)d_in[18]; const float* bias1b=(const float*)d_in[19];
  float*    out = (float*)d_out;
  _Float16* wt  = (_Float16*)d_ws;       // 684,032 B scratch, repacked every call

  setup_weights<<<(WTOT + 255)/256, 256, 0, stream>>>(
      W_in, c0a, sb0a, ss0a, c0b, sb0b, ss0b,
      c1a, sb1a, ss1a, c1b, sb1b, ss1b, wt);

  kan_forward<<<BATCH/TB, 256, 0, stream>>>(
      x, b_in, W_out, wt, bias0a, bias0b, bias1a, bias1b, out);
}

// Round 13
// 152.124 us; speedup vs baseline: 1.1345x; 1.0895x over previous
//
#include <hip/hip_runtime.h>
#include <math.h>
#include <stdint.h>

// ---------------- model constants ----------------
#define BATCH 65536
#define TB 128           // 4 waves x 32 rows (one 32x32 m-tile each), independent

typedef __fp16   fp16x2  __attribute__((ext_vector_type(2)));   // cvt_pkrtz result
typedef _Float16 half8   __attribute__((ext_vector_type(8)));
typedef float    floatx16 __attribute__((ext_vector_type(16)));

// per-wave LDS strides (halves)
#define SH 68            // hH: 64 cols + 4 pad
#define SM 130           // hM: 129 cols + 1
#define HM_SLICE (32*SM + 64)   // +64 zeroed tail halves (b128 overrun, row 31)

// packed-weight geometry (f16), FRAGMENT-ORDERED for 32x32x16:
//   element (ks, nt, lane, j) at ((ks*NT + nt)*512) + lane*8 + j
//   maps to B[k = ks*16 + (lane>>5)*8 + j][n = nt*32 + (lane&31)]
#define WIN 2048          // stage1: 2 ksteps x 2 ntiles x 512
#define KSA 36            // a: 32 spline ksteps + 4 silu
#define KSB 74            // b: 65 spline ksteps (1032 real k) + 9 silu (129 real)
#define WA (KSA*5*512)    // 92160
#define WB (KSB*2*512)    // 75776
#define WTOT (WIN + 2*(WA+WB))   // 337920 halfs = 675840 B of d_ws

// ---------------------------------------------------------------------------
// setup: pack all weights f16 in 32x32-fragment order (same mapping as r12).
// ---------------------------------------------------------------------------
__global__ void setup_weights(
    const float* __restrict__ W_in,
    const float* __restrict__ c0a, const float* __restrict__ sb0a, const float* __restrict__ ss0a,
    const float* __restrict__ c0b, const float* __restrict__ sb0b, const float* __restrict__ ss0b,
    const float* __restrict__ c1a, const float* __restrict__ sb1a, const float* __restrict__ ss1a,
    const float* __restrict__ c1b, const float* __restrict__ sb1b, const float* __restrict__ ss1b,
    _Float16* __restrict__ wt) {
  int idx = blockIdx.x * 256 + threadIdx.x;
  if (idx >= WTOT) return;
  float v = 0.0f;
  if (idx < WIN) {                        // W_in [32][64]: (ks*2+nt)*512 order
    int ks = idx >> 10; int nt = (idx >> 9) & 1;
    int q = idx & 511;  int l = q >> 3;   int j = q & 7;
    int n = nt*32 + (l & 31);
    int k = ks*16 + (l >> 5)*8 + j;
    v = W_in[k*64 + n];
  } else {
    int e2   = idx - WIN;
    int pair = (e2 >= WA + WB) ? 1 : 0;
    int e    = e2 - pair * (WA + WB);
    if (e < WA) {                         // a-type: I=64, O=129 (5 n-tiles)
      const float* coef = pair ? c1a : c0a;
      const float* sb   = pair ? sb1a : sb0a;
      const float* ss   = pair ? ss1a : ss0a;
      int ks = e / 2560; int r = e - ks*2560;
      int nt = r >> 9;   int q = r & 511;
      int l  = q >> 3;   int j = q & 7;
      int n  = nt*32 + (l & 31);
      int k  = ks*16 + (l >> 5)*8 + j;    // k < 576
      if (n < 129) {
        if (k < 512) { int i = k >> 3, p = k & 7; v = ss[i*129+n] * coef[(i*129+n)*8 + p]; }
        else         { int i = k - 512; if (i < 64) v = sb[i*129+n]; }
      }
    } else {                              // b-type: I=129, O=64 (2 n-tiles)
      const float* coef = pair ? c1b : c0b;
      const float* sb   = pair ? sb1b : sb0b;
      const float* ss   = pair ? ss1b : ss0b;
      int eb = e - WA;
      int ks = eb >> 10; int r = eb & 1023;
      int nt = r >> 9;   int q = r & 511;
      int l  = q >> 3;   int j = q & 7;
      int n  = nt*32 + (l & 31);
      int k  = ks*16 + (l >> 5)*8 + j;    // k < 1184
      if (k < 1032)      { int i = k >> 3, p = k & 7; v = ss[i*64+n] * coef[(i*64+n)*8 + p]; }
      else if (k >= 1040){ int s = k - 1040; if (s < 129) v = sb[s*64+n]; }
      // k in [1032,1040) and s >= 129: dead pad slots -> 0
    }
  }
  wt[idx] = (_Float16)v;
}

// ---------------------------------------------------------------------------
// feat8: 8 B-spline basis values of x as a ready A-fragment (8 halfs).
// r13: leaner codegen, same values/placement as r8-r12 (absmax 0.0078):
//  - w2 via symmetry w2(u) = w1(1-u)  (reuses t2)
//  - mod-64 funnel: HW 64-bit shifts mask shift[5:0], so ONE shl and ONE shr
//    cover all branches; selects route them (saves 2 shifts + 3 subs).
// ---------------------------------------------------------------------------
__device__ __forceinline__ half8 feat8(float x) {
  float s  = fmaf(x, 2.5f, 5.5f);          // (x+2.2)*2.5
  float mf = floorf(s);
  int   m  = (int)mf;
  float u  = s - mf;
  float t  = 1.0f - u;
  float u2 = u*u;
  float t2 = t*t;
  float w0 = t2 * (t * (1.0f/6.0f));
  float w3 = u2 * (u * (1.0f/6.0f));
  float w1 = fmaf(u2, fmaf(0.5f, u, -1.0f), 2.0f/3.0f);   // (3u^3-6u^2+4)/6
  float w2 = fmaf(t2, fmaf(0.5f, t, -1.0f), 2.0f/3.0f);   // symmetry: w1(t)
  union { fp16x2 h2[2]; uint64_t u64; } P;
  P.h2[0] = __builtin_amdgcn_cvt_pkrtz(w0, w1);
  P.h2[1] = __builtin_amdgcn_cvt_pkrtz(w2, w3);
  uint64_t T = ((unsigned)m <= 10u) ? P.u64 : 0ull;
  int A = (m << 4) - 48;                   // bit pos of T in 128-bit window
  uint64_t L  = T << (A & 63);             // valid A: {-48..112} step 16
  uint64_t R_ = T >> ((-A) & 63);
  uint64_t q0 = (A >= 0) ? ((A < 64) ? L : 0ull) : R_;
  uint64_t q1 = (A >= 64) ? L : ((A > 0) ? R_ : 0ull);
  union { uint64_t q[2]; half8 h; } R;
  R.q[0] = q0; R.q[1] = q1;
  return R.h;
}

// extract half #kh of dword w (khs = kh*16), as f32
__device__ __forceinline__ float extract_half(uint32_t w, int khs) {
  union { uint32_t u; _Float16 h[2]; } cv;
  cv.u = w >> khs;
  return (float)cv.h[0];
}

// cheap silu: x * rcp(1+exp(-x)) — v_rcp_f32 (~1 ulp) instead of IEEE div
__device__ __forceinline__ float silu(float x) {
  return x * __builtin_amdgcn_rcpf(1.0f + __expf(-x));
}

// ---------------------------------------------------------------------------
// one KAN layer, per-wave 32 rows = one 32x32 m-tile. A-frags in registers.
// Spline loop in groups of 8 k-steps with bulk h-reads (2x half8/group);
// zero-copy depth-2 B pipeline (consume B[ks&1], refill same slot with ks+2).
// ---------------------------------------------------------------------------
template<int KSPL, int KSIL, int NT, int SIN, int O, int SOUT>
__device__ __forceinline__ void kan_layer(
    const _Float16* __restrict__ hinw, _Float16* __restrict__ houtw,
    const _Float16* __restrict__ wt, const float* __restrict__ bias, int lane) {
  constexpr int KTOT = KSPL + KSIL;
  constexpr int NG   = KSPL / 8;            // full spline groups
  constexpr int KR   = KSPL - NG*8;         // remainder spline steps (0 or 1)
  static_assert(KR == 0 || KR == 1, "remainder must be 0/1");
  const int ln  = lane & 31;
  const int kh  = lane >> 5;
  const int khs = kh << 4;
  const half8* __restrict__ bp = (const half8*)wt + lane;   // +lane*16B
  floatx16 acc[NT];
  #pragma unroll
  for (int j = 0; j < NT; ++j)
    #pragma unroll
    for (int e = 0; e < 16; ++e) acc[j][e] = 0.0f;

  half8 B[2][NT];                           // depth-2, zero-copy slots
  #pragma unroll
  for (int d = 0; d < 2; ++d)
    #pragma unroll
    for (int j = 0; j < NT; ++j) B[d][j] = bp[(d*NT + j)*64];

  union H8 { half8 h; uint32_t d[4]; };

  // ---- spline groups: 8 k-steps each; inputs 16g..16g+15 of row ln ----
  #pragma unroll 1
  for (int g = 0; g < NG; ++g) {
    H8 ha, hb;
    ha.h = *(const half8*)&hinw[ln*SIN + g*16];
    hb.h = *(const half8*)&hinw[ln*SIN + g*16 + 8];
    #pragma unroll
    for (int u = 0; u < 8; ++u) {
      uint32_t w = (u < 4) ? ha.d[u] : hb.d[u & 3];
      half8 A = feat8(extract_half(w, khs));     // input i = 2(g*8+u)+kh
      #pragma unroll
      for (int j = 0; j < NT; ++j)
        acc[j] = __builtin_amdgcn_mfma_f32_32x32x16_f16(A, B[u & 1][j], acc[j], 0, 0, 0);
      #pragma unroll
      for (int j = 0; j < NT; ++j)               // refill same slot with ks+2
        B[u & 1][j] = bp[((g*8 + u + 2)*NT + j)*64];
    }
  }

  // ---- remainder spline step (layer-b: ks = NG*8) ----
  if (KR == 1) {
    constexpr int ks = NG*8;
    H8 hc;
    hc.h = *(const half8*)&hinw[ln*SIN + ks*2];  // elems 2ks..2ks+7 (pads zeroed)
    half8 A = feat8(extract_half(hc.d[0], khs));
    #pragma unroll
    for (int j = 0; j < NT; ++j)
      acc[j] = __builtin_amdgcn_mfma_f32_32x32x16_f16(A, B[ks & 1][j], acc[j], 0, 0, 0);
    #pragma unroll
    for (int j = 0; j < NT; ++j)
      B[ks & 1][j] = bp[((ks + 2)*NT + j)*64];   // ks+2 < KTOT (KSIL >= 4... 9)
  }

  // ---- silu k-steps (fully unrolled; slots compile-time) ----
  #pragma unroll
  for (int sk = 0; sk < KSIL; ++sk) {
    const int ks = KSPL + sk;
    half8 h8 = *(const half8*)&hinw[ln*SIN + sk*16 + kh*8];
    union { fp16x2 h2[4]; half8 v; } Au;
    #pragma unroll
    for (int e = 0; e < 4; ++e) {
      float s0 = silu((float)h8[2*e]);
      float s1 = silu((float)h8[2*e + 1]);
      Au.h2[e] = __builtin_amdgcn_cvt_pkrtz(s0, s1);
    }
    #pragma unroll
    for (int j = 0; j < NT; ++j)
      acc[j] = __builtin_amdgcn_mfma_f32_32x32x16_f16(Au.v, B[ks & 1][j], acc[j], 0, 0, 0);
    const int nks = (ks + 2 < KTOT) ? (ks + 2) : (KTOT - 1);
    #pragma unroll
    for (int j = 0; j < NT; ++j)
      B[ks & 1][j] = bp[(nks*NT + j)*64];
  }

  // ---- epilogue: C/D col=lane&31, row=(reg&3)+8*(reg>>2)+4*(lane>>5) ----
  #pragma unroll
  for (int j = 0; j < NT; ++j) {
    int col = j*32 + ln;
    if (col < O) {
      float bv = bias[col];
      #pragma unroll
      for (int r = 0; r < 16; ++r) {
        int row = (r & 3) + 8*(r >> 2) + 4*kh;
        houtw[row*SOUT + col] = (_Float16)(acc[j][r] + bv);
      }
    }
  }
}

// ---------------------------------------------------------------------------
// fused forward, zero __syncthreads, 32x32 MFMA, zero-copy depth-2 pipeline.
// LDS = 51200 B -> 2 blocks/CU; grid 512 = exact.
// ---------------------------------------------------------------------------
extern "C" __global__ void __launch_bounds__(256, 2)
kan_forward(const float* __restrict__ x, const float* __restrict__ b_in,
            const float* __restrict__ W_out, const _Float16* __restrict__ wt,
            const float* __restrict__ bias0a, const float* __restrict__ bias0b,
            const float* __restrict__ bias1a, const float* __restrict__ bias1b,
            float* __restrict__ out) {
  __shared__ _Float16 hM[4][HM_SLICE];
  __shared__ _Float16 hH[4][32*SH];
  const int t    = threadIdx.x;
  const int wv   = t >> 6;
  const int lane = t & 63;
  const int ln   = lane & 31;
  const int kh   = lane >> 5;
  _Float16* hMw = hM[wv];
  _Float16* hHw = hH[wv];
  const int rbase = blockIdx.x * TB + wv * 32;

  // zero hM spots padded reads can touch: col 129 each row + tail pad
  hMw[32*SM + lane] = (_Float16)0.0f;
  if (lane < 32) hMw[lane*SM + 129] = (_Float16)0.0f;

  // stage 1: hH = relu(x @ W_in + b_in). Two k-steps, 2 n-tiles.
  {
    const float* xr = &x[(rbase + ln)*32 + kh*8];
    float4 v0 = *(const float4*)&xr[0];
    float4 v1 = *(const float4*)&xr[4];
    float4 v2 = *(const float4*)&xr[16];
    float4 v3 = *(const float4*)&xr[20];
    union { fp16x2 h2[4]; half8 h8; } A0, A1;
    A0.h2[0] = __builtin_amdgcn_cvt_pkrtz(v0.x, v0.y);
    A0.h2[1] = __builtin_amdgcn_cvt_pkrtz(v0.z, v0.w);
    A0.h2[2] = __builtin_amdgcn_cvt_pkrtz(v1.x, v1.y);
    A0.h2[3] = __builtin_amdgcn_cvt_pkrtz(v1.z, v1.w);
    A1.h2[0] = __builtin_amdgcn_cvt_pkrtz(v2.x, v2.y);
    A1.h2[1] = __builtin_amdgcn_cvt_pkrtz(v2.z, v2.w);
    A1.h2[2] = __builtin_amdgcn_cvt_pkrtz(v3.x, v3.y);
    A1.h2[3] = __builtin_amdgcn_cvt_pkrtz(v3.z, v3.w);
    const half8* bp = (const half8*)wt + lane;
    #pragma unroll
    for (int nt = 0; nt < 2; ++nt) {
      floatx16 a;
      #pragma unroll
      for (int e = 0; e < 16; ++e) a[e] = 0.0f;
      a = __builtin_amdgcn_mfma_f32_32x32x16_f16(A0.h8, bp[nt*64],       a, 0, 0, 0);
      a = __builtin_amdgcn_mfma_f32_32x32x16_f16(A1.h8, bp[(2 + nt)*64], a, 0, 0, 0);
      int col = nt*32 + ln;
      float bv = b_in[col];
      #pragma unroll
      for (int r = 0; r < 16; ++r) {
        int row = (r & 3) + 8*(r >> 2) + 4*kh;
        hHw[row*SH + col] = (_Float16)fmaxf(a[r] + bv, 0.0f);
      }
    }
  }

  kan_layer<32,4,5,SH,129,SM>(hHw, hMw, wt + WIN,             bias0a, lane);
  kan_layer<65,9,2,SM, 64,SH>(hMw, hHw, wt + WIN + WA,        bias0b, lane);
  kan_layer<32,4,5,SH,129,SM>(hHw, hMw, wt + WIN + WA + WB,   bias1a, lane);
  kan_layer<65,9,2,SM, 64,SH>(hMw, hHw, wt + WIN + 2*WA + WB, bias1b, lane);

  // final: out = sigmoid(hH @ W_out); two col-halves reduced by shuffle
  {
    float s = 0.0f;
    #pragma unroll
    for (int j = 0; j < 32; ++j)
      s = fmaf((float)hHw[ln*SH + kh*32 + j], W_out[kh*32 + j], s);
    s += __shfl_down(s, 32);
    if (lane < 32)
      out[rbase + ln] = __builtin_amdgcn_rcpf(1.0f + __expf(-s));
  }
}

// ---------------------------------------------------------------------------
extern "C" void kernel_launch(void* const* d_in, const int* in_sizes, int n_in,
                              void* d_out, int out_size, void* d_ws, size_t ws_size,
                              hipStream_t stream) {
  const float* x     = (const float*)d_in[0];
  const float* W_in  = (const float*)d_in[1];
  const float* b_in  = (const float*)d_in[2];
  const float* W_out = (const float*)d_in[3];
  const float* c0a = (const float*)d_in[4];  const float* sb0a = (const float*)d_in[5];
  const float* ss0a= (const float*)d_in[6];  const float* bias0a=(const float*)d_in[7];
  const float* c0b = (const float*)d_in[8];  const float* sb0b = (const float*)d_in[9];
  const float* ss0b= (const float*)d_in[10]; const float* bias0b=(const float*)d_in[11];
  const float* c1a = (const float*)d_in[12]; const float* sb1a = (const float*)d_in[13];
  const float* ss1a= (const float*)d_in[14]; const float* bias1a=(const float*)d_in[15];
  const float* c1b = (const float*)d_in[16]; const float* sb1b = (const float*)d_in[17];
  const float* ss1b= (const float*)d_in[18]; const float* bias1b=(const float*)d_in[19];
  float*    out = (float*)d_out;
  _Float16* wt  = (_Float16*)d_ws;       // 675,840 B scratch, repacked every call

  setup_weights<<<(WTOT + 255)/256, 256, 0, stream>>>(
      W_in, c0a, sb0a, ss0a, c0b, sb0b, ss0b,
      c1a, sb1a, ss1a, c1b, sb1b, ss1b, wt);

  kan_forward<<<BATCH/TB, 256, 0, stream>>>(
      x, b_in, W_out, wt, bias0a, bias0b, bias1a, bias1b, out);
}